// Round 1
// baseline (619.654 us; speedup 1.0000x reference)
//
#include <hip/hip_runtime.h>
#include <hip/hip_fp16.h>

typedef _Float16 h2f __attribute__((ext_vector_type(2)));

__device__ __forceinline__ float dot2f(unsigned a, unsigned b, float c) {
#if __has_builtin(__builtin_amdgcn_fdot2)
  return __builtin_amdgcn_fdot2(__builtin_bit_cast(h2f, a),
                                __builtin_bit_cast(h2f, b), c, false);
#else
  h2f x = __builtin_bit_cast(h2f, a);
  h2f y = __builtin_bit_cast(h2f, b);
  return c + (float)x[0] * (float)y[0] + (float)x[1] * (float)y[1];
#endif
}

__device__ __forceinline__ float sigf(float x) { return 1.0f / (1.0f + __expf(-x)); }
__device__ __forceinline__ float tanhfast(float x) {
  float e = __expf(-2.0f * fabsf(x));
  float r = (1.0f - e) / (1.0f + e);
  return (x < 0.0f) ? -r : r;
}
__device__ __forceinline__ float lrelu(float x) { return x > 0.0f ? x : 0.2f * x; }

// ---------------------------------------------------------------------------
// prep: transposes + fp16 packing + rWi prefix sums (runs every call; cheap)
// ---------------------------------------------------------------------------
__global__ void k_prep(const float* __restrict__ conv_w, const float* __restrict__ gWi,
                       const float* __restrict__ gWh, const float* __restrict__ rWh,
                       const float* __restrict__ rWi,
                       float* __restrict__ cwT, float* __restrict__ gWiT,
                       unsigned* __restrict__ gWhP, unsigned* __restrict__ rWhP,
                       float* __restrict__ pref) {
  const int N0 = 64 * 64 * 7;     // cwT  [i][s][k]
  const int N1 = 192 * 450;       // gWiT [d][g]
  const int N2 = 76 * 450;        // gWhP [jj][g] packed half2 (zero-pad j>=150)
  const int N3 = 76 * 450;        // rWhP
  const int N4 = 450;             // pref scan, one thread per g
  int total = N0 + N1 + N2 + N3 + N4;
  for (int idx = blockIdx.x * blockDim.x + threadIdx.x; idx < total;
       idx += gridDim.x * blockDim.x) {
    if (idx < N0) {
      int k = idx & 63; int is = idx >> 6; int i = is / 7; int s = is - i * 7;
      cwT[idx] = conv_w[(k * 64 + i) * 7 + s];
    } else if (idx < N0 + N1) {
      int j = idx - N0; int g = j % 450; int d = j / 450;
      gWiT[j] = gWi[g * 192 + d];
    } else if (idx < N0 + N1 + N2) {
      int j = idx - (N0 + N1); int g = j % 450; int jj = j / 450;
      int j0 = 2 * jj, j1 = 2 * jj + 1;
      float a = (j0 < 150) ? gWh[g * 150 + j0] : 0.f;
      float b = (j1 < 150) ? gWh[g * 150 + j1] : 0.f;
      __half2 h = __floats2half2_rn(a, b);
      gWhP[j] = *reinterpret_cast<unsigned*>(&h);
    } else if (idx < N0 + N1 + N2 + N3) {
      int j = idx - (N0 + N1 + N2); int g = j % 450; int jj = j / 450;
      int j0 = 2 * jj, j1 = 2 * jj + 1;
      float a = (j0 < 150) ? rWh[g * 150 + j0] : 0.f;
      float b = (j1 < 150) ? rWh[g * 150 + j1] : 0.f;
      __half2 h = __floats2half2_rn(a, b);
      rWhP[j] = *reinterpret_cast<unsigned*>(&h);
    } else {
      int g = idx - (N0 + N1 + N2 + N3);
      float run = 0.f;
      pref[g] = 0.f;
      for (int j = 0; j < 150; ++j) { run += rWi[g * 150 + j]; pref[(j + 1) * 450 + g] = run; }
    }
  }
}

// ---------------------------------------------------------------------------
// conv1d (KS=7, pad 3) + bias + relu.  block=(4 t-groups x 64 k), 16 t/block
// ---------------------------------------------------------------------------
__global__ __launch_bounds__(256) void k_conv(const float* __restrict__ x,
                                              const float* __restrict__ cwT,
                                              const float* __restrict__ conv_b,
                                              float* __restrict__ xc) {
  __shared__ float xs[22 * 64];
  int b = blockIdx.y, t0 = blockIdx.x * 16, tid = threadIdx.x;
  for (int l = tid; l < 22 * 64; l += 256) {
    int r = l >> 6, i = l & 63;
    int t = t0 - 3 + r;
    xs[l] = (t >= 0 && t < 256) ? x[(b * 256 + t) * 64 + i] : 0.f;
  }
  __syncthreads();
  int k = tid & 63, tg = tid >> 6;
  float bias = conv_b[k];
  float acc[4] = {bias, bias, bias, bias};
  for (int i = 0; i < 64; ++i) {
#pragma unroll
    for (int s = 0; s < 7; ++s) {
      float wv = cwT[(i * 7 + s) * 64 + k];
#pragma unroll
      for (int q = 0; q < 4; ++q)
        acc[q] += xs[(tg * 4 + q + s) * 64 + i] * wv;
    }
  }
#pragma unroll
  for (int q = 0; q < 4; ++q)
    xc[(b * 256 + t0 + tg * 4 + q) * 64 + k] = fmaxf(acc[q], 0.f);
}

// ---------------------------------------------------------------------------
// feature-GAT g1/g2: (b,i) rows over 256-dim, e=512 wide.  8 i per block.
// g2 stored transposed [b][e][i] so attention reads coalesce.
// ---------------------------------------------------------------------------
__global__ __launch_bounds__(512) void k_featg(const float* __restrict__ xc,
                                               const float* __restrict__ fW,
                                               const float* __restrict__ fb,
                                               float* __restrict__ g1f,
                                               float* __restrict__ g2fT) {
  __shared__ float xsL[256 * 8];
  int b = blockIdx.y, i0 = blockIdx.x * 8, e = threadIdx.x;
  for (int l = e; l < 2048; l += 512) {
    int t = l >> 3, ii = l & 7;
    xsL[l] = xc[(b * 256 + t) * 64 + i0 + ii];
  }
  __syncthreads();
  float a1[8] = {}, a2[8] = {};
  for (int t = 0; t < 256; ++t) {
    float w1 = fW[t * 512 + e];
    float w2 = fW[(256 + t) * 512 + e];
#pragma unroll
    for (int ii = 0; ii < 8; ++ii) {
      float s = xsL[t * 8 + ii];
      a1[ii] += s * w1; a2[ii] += s * w2;
    }
  }
  float fbe = fb[e];
#pragma unroll
  for (int ii = 0; ii < 8; ++ii)
    g1f[(b * 64 + i0 + ii) * 512 + e] = a1[ii];
  float4 v0 = make_float4(a2[0] + fbe, a2[1] + fbe, a2[2] + fbe, a2[3] + fbe);
  float4 v1 = make_float4(a2[4] + fbe, a2[5] + fbe, a2[6] + fbe, a2[7] + fbe);
  float4* p = reinterpret_cast<float4*>(&g2fT[(b * 512 + e) * 64 + i0]);
  p[0] = v0; p[1] = v1;
}

// ---------------------------------------------------------------------------
// feature-GAT attention: block=(b,i). e_j (512-dot) -> softmax64 -> att@x -> sig
// ---------------------------------------------------------------------------
__global__ __launch_bounds__(256) void k_feata(const float* __restrict__ xc,
                                               const float* __restrict__ g1f,
                                               const float* __restrict__ g2fT,
                                               const float* __restrict__ fa,
                                               const float* __restrict__ fbias,
                                               float* __restrict__ h_feat) {
  __shared__ float g1L[512], faL[512], part[4 * 64], attL[64];
  int b = blockIdx.y, i = blockIdx.x, tid = threadIdx.x;
  for (int l = tid; l < 512; l += 256) {
    g1L[l] = g1f[(b * 64 + i) * 512 + l];
    faL[l] = fa[l];
  }
  __syncthreads();
  int q = tid >> 6, j = tid & 63;
  float acc = 0.f;
  for (int e = q * 128; e < q * 128 + 128; ++e) {
    float z = g1L[e] + g2fT[(b * 512 + e) * 64 + j];
    acc += faL[e] * lrelu(z);
  }
  part[q * 64 + j] = acc;
  __syncthreads();
  if (tid < 64) {
    float ev = part[tid] + part[64 + tid] + part[128 + tid] + part[192 + tid] +
               fbias[i * 64 + tid];
    float m = ev;
#pragma unroll
    for (int off = 32; off > 0; off >>= 1) m = fmaxf(m, __shfl_xor(m, off));
    float p = __expf(ev - m);
    float s = p;
#pragma unroll
    for (int off = 32; off > 0; off >>= 1) s += __shfl_xor(s, off);
    attL[tid] = p / s;
  }
  __syncthreads();
  float o = 0.f;
  for (int jj = 0; jj < 64; ++jj)
    o += attL[jj] * xc[(b * 256 + tid) * 64 + jj];
  h_feat[(b * 256 + tid) * 64 + i] = sigf(o);
}

// ---------------------------------------------------------------------------
// temporal-GAT g1/g2: rows (b,t), e=128 wide. 16 t per block, g2 transposed.
// ---------------------------------------------------------------------------
__global__ __launch_bounds__(256) void k_tempg(const float* __restrict__ xc,
                                               const float* __restrict__ tW,
                                               const float* __restrict__ tb,
                                               float* __restrict__ g1t,
                                               float* __restrict__ g2tT) {
  __shared__ float xsL[16 * 64];
  int b = blockIdx.y, t0 = blockIdx.x * 16, tid = threadIdx.x;
  int e = tid & 127, th = tid >> 7;
  for (int l = tid; l < 1024; l += 256)
    xsL[l] = xc[(b * 256 + t0) * 64 + l];
  __syncthreads();
  float a1[8] = {}, a2[8] = {};
  for (int k = 0; k < 64; ++k) {
    float w1 = tW[k * 128 + e];
    float w2 = tW[(64 + k) * 128 + e];
#pragma unroll
    for (int tt = 0; tt < 8; ++tt) {
      float s = xsL[(th * 8 + tt) * 64 + k];
      a1[tt] += s * w1; a2[tt] += s * w2;
    }
  }
  float tbe = tb[e];
#pragma unroll
  for (int tt = 0; tt < 8; ++tt)
    g1t[(b * 256 + t0 + th * 8 + tt) * 128 + e] = a1[tt];
  float4 v0 = make_float4(a2[0] + tbe, a2[1] + tbe, a2[2] + tbe, a2[3] + tbe);
  float4 v1 = make_float4(a2[4] + tbe, a2[5] + tbe, a2[6] + tbe, a2[7] + tbe);
  float4* p = reinterpret_cast<float4*>(&g2tT[(b * 128 + e) * 256 + t0 + th * 8]);
  p[0] = v0; p[1] = v1;
}

// ---------------------------------------------------------------------------
// temporal-GAT attention: block=(b, 4 rows i). e_j over j=256 (128-dot),
// per-wave softmax (wave w owns row w), then att@x (j=256) + sigmoid.
// ---------------------------------------------------------------------------
__global__ __launch_bounds__(256) void k_tempa(const float* __restrict__ xc,
                                               const float* __restrict__ g1t,
                                               const float* __restrict__ g2tT,
                                               const float* __restrict__ ta,
                                               const float* __restrict__ tbias,
                                               float* __restrict__ h_temp) {
  __shared__ float g1L[4 * 128], taL[128], eL[4 * 256];
  int b = blockIdx.y, i0 = blockIdx.x * 4, tid = threadIdx.x;
  for (int l = tid; l < 512; l += 256)
    g1L[l] = g1t[(b * 256 + i0) * 128 + l];
  if (tid < 128) taL[tid] = ta[tid];
  __syncthreads();
  float acc[4] = {};
  for (int e = 0; e < 128; ++e) {
    float g2 = g2tT[(b * 128 + e) * 256 + tid];
    float tae = taL[e];
#pragma unroll
    for (int ii = 0; ii < 4; ++ii)
      acc[ii] += tae * lrelu(g1L[ii * 128 + e] + g2);
  }
#pragma unroll
  for (int ii = 0; ii < 4; ++ii)
    eL[ii * 256 + tid] = acc[ii] + tbias[(i0 + ii) * 256 + tid];
  __syncthreads();
  int wv = tid >> 6, ln = tid & 63;
  {
    float v0 = eL[wv * 256 + ln], v1 = eL[wv * 256 + 64 + ln];
    float v2 = eL[wv * 256 + 128 + ln], v3 = eL[wv * 256 + 192 + ln];
    float m = fmaxf(fmaxf(v0, v1), fmaxf(v2, v3));
#pragma unroll
    for (int off = 32; off > 0; off >>= 1) m = fmaxf(m, __shfl_xor(m, off));
    float p0 = __expf(v0 - m), p1 = __expf(v1 - m);
    float p2 = __expf(v2 - m), p3 = __expf(v3 - m);
    float s = p0 + p1 + p2 + p3;
#pragma unroll
    for (int off = 32; off > 0; off >>= 1) s += __shfl_xor(s, off);
    float rs = 1.f / s;
    eL[wv * 256 + ln] = p0 * rs; eL[wv * 256 + 64 + ln] = p1 * rs;
    eL[wv * 256 + 128 + ln] = p2 * rs; eL[wv * 256 + 192 + ln] = p3 * rs;
  }
  __syncthreads();
  int ii = tid >> 6, k = tid & 63;
  float o = 0.f;
  for (int j = 0; j < 256; ++j)
    o += eL[ii * 256 + j] * xc[(b * 256 + j) * 64 + k];
  h_temp[(b * 256 + i0 + ii) * 64 + k] = sigf(o);
}

// ---------------------------------------------------------------------------
// xW = concat(xc,h_feat,h_temp) @ gWi^T + gbi   (4096x192)@(192x450)
// ---------------------------------------------------------------------------
__global__ __launch_bounds__(256) void k_xw(const float* __restrict__ xc,
                                            const float* __restrict__ h_feat,
                                            const float* __restrict__ h_temp,
                                            const float* __restrict__ gWiT,
                                            const float* __restrict__ gbi,
                                            float* __restrict__ xW) {
  __shared__ float hc[16 * 192];
  int b = blockIdx.z, t0 = blockIdx.y * 16, g0 = blockIdx.x * 128;
  int tid = threadIdx.x;
  for (int l = tid; l < 16 * 192; l += 256) {
    int tt = l / 192, d = l - tt * 192;
    int row = (b * 256 + t0 + tt) * 64;
    float v;
    if (d < 64) v = xc[row + d];
    else if (d < 128) v = h_feat[row + d - 64];
    else v = h_temp[row + d - 128];
    hc[l] = v;
  }
  __syncthreads();
  int gl = tid & 127, th = tid >> 7;
  int g = g0 + gl;
  if (g < 450) {
    float acc[8] = {};
    for (int d = 0; d < 192; ++d) {
      float w = gWiT[d * 450 + g];
#pragma unroll
      for (int tt = 0; tt < 8; ++tt)
        acc[tt] += hc[(th * 8 + tt) * 192 + d] * w;
    }
    float bi = gbi[g];
#pragma unroll
    for (int tt = 0; tt < 8; ++tt)
      xW[(b * 256 + t0 + th * 8 + tt) * 450 + g] = acc[tt] + bi;
  }
}

// ---------------------------------------------------------------------------
// decoder xW: h_rep[b,t,j] = h_end[b,(150t+j)>>8] -> closed form w/ prefix sums
// ---------------------------------------------------------------------------
__global__ __launch_bounds__(512) void k_xwdec(const float* __restrict__ h_end,
                                               const float* __restrict__ pref,
                                               const float* __restrict__ rbi,
                                               float* __restrict__ xwD) {
  __shared__ float heL[160];
  int b = blockIdx.y, t0 = blockIdx.x * 16, g = threadIdx.x;
  if (g < 160) heL[g] = (g < 150) ? h_end[b * 150 + g] : 0.f;
  __syncthreads();
  if (g < 450) {
    float tot = pref[150 * 450 + g];
    float bi = rbi[g];
#pragma unroll 4
    for (int tt = 0; tt < 16; ++tt) {
      int t = t0 + tt;
      int base = 150 * t;
      int a = base >> 8;
      int c = 256 * (a + 1) - base; if (c > 150) c = 150;
      float pv = pref[c * 450 + g];
      xwD[(b * 256 + t) * 450 + g] = bi + heL[a] * pv + heL[a + 1] * (tot - pv);
    }
  }
}

// ---------------------------------------------------------------------------
// GRU scan: one block per batch element. Wh held in registers as packed fp16
// pairs, h broadcast from LDS via ds_read_b128, v_dot2_f32_f16 accumulate.
// mode 0: encoder (writes h_end). mode 1: decoder (writes dec_out rows).
// ---------------------------------------------------------------------------
__global__ __launch_bounds__(512) void k_gru(const float* __restrict__ xwAll,
                                             const unsigned* __restrict__ WhP,
                                             const float* __restrict__ bh,
                                             float* __restrict__ h_end,
                                             float* __restrict__ dec_out,
                                             int mode) {
  __shared__ __align__(16) unsigned hPair[80];   // 152 padded halves (zeros at 150..)
  __shared__ float hL32[152], rL[152], zL[152];
  int b = blockIdx.x, tid = threadIdx.x;
  if (tid < 80) hPair[tid] = 0u;
  if (tid < 152) hL32[tid] = 0.f;
  unsigned w[76];
  float bhv = 0.f;
  if (tid < 450) {
#pragma unroll
    for (int jj = 0; jj < 76; ++jj) w[jj] = WhP[jj * 450 + tid];
    bhv = bh[tid];
  }
  const float* xwrow = xwAll + (size_t)(b * 256) * 450;
  __syncthreads();
  const uint4* hp4 = reinterpret_cast<const uint4*>(hPair);
  for (int t = 0; t < 256; ++t) {
    float xwv = 0.f, acc = bhv;
    if (tid < 450) {
      xwv = xwrow[t * 450 + tid];
      float acc2 = 0.f;
#pragma unroll
      for (int q = 0; q < 19; ++q) {
        uint4 hv = hp4[q];
        acc  = dot2f(hv.x, w[4 * q + 0], acc);
        acc2 = dot2f(hv.y, w[4 * q + 1], acc2);
        acc  = dot2f(hv.z, w[4 * q + 2], acc);
        acc2 = dot2f(hv.w, w[4 * q + 3], acc2);
      }
      acc += acc2;   // acc = gh[g] (includes bh)
    }
    if (tid < 150) rL[tid] = sigf(xwv + acc);
    else if (tid < 300) zL[tid - 150] = sigf(xwv + acc);
    __syncthreads();
    if (tid >= 300 && tid < 450) {
      int i2 = tid - 300;
      float n = tanhfast(xwv + rL[i2] * acc);
      float z = zL[i2];
      float hn = (1.f - z) * n + z * hL32[i2];
      hL32[i2] = hn;
      reinterpret_cast<__half*>(hPair)[i2] = __float2half(hn);
      if (mode == 1) dec_out[((size_t)(b * 256) + t) * 150 + i2] = hn;
    }
    __syncthreads();
  }
  if (mode == 0 && tid < 150) h_end[b * 150 + tid] = hL32[tid];
}

// ---------------------------------------------------------------------------
// predictions = relu(h_end@f0w+f0b)@f1w+f1b  (one block per b)
// ---------------------------------------------------------------------------
__global__ __launch_bounds__(192) void k_pred(const float* __restrict__ h_end,
                                              const float* __restrict__ f0w,
                                              const float* __restrict__ f0b,
                                              const float* __restrict__ f1w,
                                              const float* __restrict__ f1b,
                                              float* __restrict__ out) {
  __shared__ float heL[152], t1L[152];
  int b = blockIdx.x, tid = threadIdx.x;
  if (tid < 152) heL[tid] = (tid < 150) ? h_end[b * 150 + tid] : 0.f;
  __syncthreads();
  if (tid < 150) {
    float a = f0b[tid];
    for (int i = 0; i < 150; ++i) a += heL[i] * f0w[i * 150 + tid];
    t1L[tid] = fmaxf(a, 0.f);
  }
  if (tid >= 150 && tid < 152) t1L[tid] = 0.f;
  __syncthreads();
  if (tid < 64) {
    float a = f1b[tid];
    for (int j = 0; j < 150; ++j) a += t1L[j] * f1w[j * 64 + tid];
    out[b * 64 + tid] = a;
  }
}

// ---------------------------------------------------------------------------
// recons = dec_out @ rfw + rfb   (4 rows per block)
// ---------------------------------------------------------------------------
__global__ __launch_bounds__(256) void k_recon(const float* __restrict__ dec_out,
                                               const float* __restrict__ rfw,
                                               const float* __restrict__ rfb,
                                               float* __restrict__ out) {
  int row = blockIdx.x * 4 + (threadIdx.x >> 6);
  int k = threadIdx.x & 63;
  const float* d = dec_out + (size_t)row * 150;
  float a = rfb[k];
  for (int j = 0; j < 150; ++j) a += d[j] * rfw[j * 64 + k];
  out[1024 + (size_t)row * 64 + k] = a;
}

extern "C" void kernel_launch(void* const* d_in, const int* in_sizes, int n_in,
                              void* d_out, int out_size, void* d_ws, size_t ws_size,
                              hipStream_t stream) {
  (void)in_sizes; (void)n_in; (void)out_size; (void)ws_size;
  const float* x      = (const float*)d_in[0];
  const float* conv_w = (const float*)d_in[1];
  const float* conv_b = (const float*)d_in[2];
  const float* fW     = (const float*)d_in[3];
  const float* fb     = (const float*)d_in[4];
  const float* fa     = (const float*)d_in[5];
  const float* fbias  = (const float*)d_in[6];
  const float* tW     = (const float*)d_in[7];
  const float* tb     = (const float*)d_in[8];
  const float* ta     = (const float*)d_in[9];
  const float* tbias  = (const float*)d_in[10];
  const float* gWi    = (const float*)d_in[11];
  const float* gWh    = (const float*)d_in[12];
  const float* gbi    = (const float*)d_in[13];
  const float* gbh    = (const float*)d_in[14];
  const float* f0w    = (const float*)d_in[15];
  const float* f0b    = (const float*)d_in[16];
  const float* f1w    = (const float*)d_in[17];
  const float* f1b    = (const float*)d_in[18];
  const float* rWi    = (const float*)d_in[19];
  const float* rWh    = (const float*)d_in[20];
  const float* rbi    = (const float*)d_in[21];
  const float* rbh    = (const float*)d_in[22];
  const float* rfw    = (const float*)d_in[23];
  const float* rfb    = (const float*)d_in[24];
  float* out = (float*)d_out;
  float* ws  = (float*)d_ws;

  // workspace layout (floats). XW/XWD alias the dead GAT g-buffers.
  float* XC   = ws;                   // 262144
  float* HF   = XC + 262144;          // 262144
  float* HT   = HF + 262144;          // 262144
  float* GBUF = HT + 262144;          // 2097152 (g1f,g2fT,g1t,g2tT) -> later XW/XWD
  float* G1F  = GBUF;
  float* G2FT = GBUF + 524288;
  float* G1T  = GBUF + 1048576;
  float* G2TT = GBUF + 1572864;
  float* XW   = GBUF;                 // alias: GAT g-buffers dead by then (1843200)
  float* XWD  = GBUF;                 // alias: XW dead after encoder
  float* HEND = GBUF + 2097152;       // 2400
  float* DEC  = HEND + 2400;          // 614400
  float* CWT  = DEC + 614400;         // 28672
  float* GWIT = CWT + 28672;          // 86400
  unsigned* GWHP = (unsigned*)(GWIT + 86400);  // 34200
  unsigned* RWHP = GWHP + 34200;               // 34200
  float* PREF = (float*)(RWHP + 34200);        // 67950

  k_prep<<<512, 256, 0, stream>>>(conv_w, gWi, gWh, rWh, rWi, CWT, GWIT, GWHP, RWHP, PREF);
  k_conv<<<dim3(16, 16), 256, 0, stream>>>(x, CWT, conv_b, XC);
  k_featg<<<dim3(8, 16), 512, 0, stream>>>(XC, fW, fb, G1F, G2FT);
  k_tempg<<<dim3(16, 16), 256, 0, stream>>>(XC, tW, tb, G1T, G2TT);
  k_feata<<<dim3(64, 16), 256, 0, stream>>>(XC, G1F, G2FT, fa, fbias, HF);
  k_tempa<<<dim3(64, 16), 256, 0, stream>>>(XC, G1T, G2TT, ta, tbias, HT);
  k_xw<<<dim3(4, 16, 16), 256, 0, stream>>>(XC, HF, HT, GWIT, gbi, XW);
  k_gru<<<16, 512, 0, stream>>>(XW, GWHP, gbh, HEND, nullptr, 0);
  k_pred<<<16, 192, 0, stream>>>(HEND, f0w, f0b, f1w, f1b, out);
  k_xwdec<<<dim3(16, 16), 512, 0, stream>>>(HEND, PREF, rbi, XWD);
  k_gru<<<16, 512, 0, stream>>>(XWD, RWHP, rbh, nullptr, DEC, 1);
  k_recon<<<1024, 256, 0, stream>>>(DEC, rfw, rfb, out);
}